// Round 7
// baseline (262.189 us; speedup 1.0000x reference)
//
#include <hip/hip_runtime.h>
#include <hip/hip_bf16.h>

#define RELS 7
#define DIM 64
#define KTOT 512  // 7*64 + 64 (root)

typedef __attribute__((ext_vector_type(8))) short short8;
typedef __attribute__((ext_vector_type(4))) float floatx4;

__device__ inline unsigned short f2b(float f) {
  union { float f; unsigned u; } v; v.f = f;
  unsigned u = v.u + 0x7fffu + ((v.u >> 16) & 1u);  // round-nearest-even
  return (unsigned short)(u >> 16);
}
__device__ inline float b2f(unsigned short b) {
  union { unsigned u; float f; } v; v.u = ((unsigned)b) << 16;
  return v.f;
}
__device__ inline float u2f(unsigned u) {
  union { unsigned u; float f; } v; v.u = u;
  return v.f;
}

// x f32 -> bf16 (8 elems/thread)
__global__ void __launch_bounds__(256) k_xb(const float* __restrict__ x,
                                            unsigned short* __restrict__ xb, long n8) {
  long t = (long)blockIdx.x * 256 + threadIdx.x;
  if (t >= n8) return;
  const float4* p = reinterpret_cast<const float4*>(x + t * 8);
  float4 f0 = p[0], f1 = p[1];
  short8 o;
  o[0] = (short)f2b(f0.x); o[1] = (short)f2b(f0.y);
  o[2] = (short)f2b(f0.z); o[3] = (short)f2b(f0.w);
  o[4] = (short)f2b(f1.x); o[5] = (short)f2b(f1.y);
  o[6] = (short)f2b(f1.z); o[7] = (short)f2b(f1.w);
  *reinterpret_cast<short8*>(xb + t * 8) = o;
}

// [W;root] f32 -> bf16 in MFMA-fragment order (one-time, 64 KiB)
__global__ void __launch_bounds__(256) k_wb(const float* __restrict__ W,
                                            const float* __restrict__ root,
                                            unsigned short* __restrict__ Blg) {
  int g = blockIdx.x * 256 + threadIdx.x;  // 4096 groups
  if (g >= 4096) return;
  int kb = g >> 6, col = g & 63;
  short8 tmp;
#pragma unroll
  for (int j = 0; j < 8; ++j) {
    int k = kb * 8 + j;
    float w = (k < 448) ? W[k * 64 + col] : root[(k - 448) * 64 + col];
    tmp[j] = (short)f2b(w);
  }
  *reinterpret_cast<short8*>(&Blg[g * 8]) = tmp;
}

// histogram over (dst*8 + rel)
__global__ void __launch_bounds__(256) k_hist(const int* __restrict__ dst,
                                              const int* __restrict__ et,
                                              int* __restrict__ deg, int E) {
  int e = blockIdx.x * 256 + threadIdx.x;
  if (e < E) atomicAdd(&deg[(dst[e] << 3) + et[e]], 1);
}

// block-local exclusive scan over 1024 entries (256 thr x 4)
__global__ void __launch_bounds__(256) k_scan1(const int* __restrict__ deg,
                                               int* __restrict__ start,
                                               int* __restrict__ bsum, int n) {
  __shared__ int sm[256];
  int t = threadIdx.x;
  int base = blockIdx.x * 1024 + t * 4;
  int v0 = (base + 0 < n) ? deg[base + 0] : 0;
  int v1 = (base + 1 < n) ? deg[base + 1] : 0;
  int v2 = (base + 2 < n) ? deg[base + 2] : 0;
  int v3 = (base + 3 < n) ? deg[base + 3] : 0;
  int s = v0 + v1 + v2 + v3;
  sm[t] = s;
  __syncthreads();
  for (int off = 1; off < 256; off <<= 1) {
    int a = (t >= off) ? sm[t - off] : 0;
    __syncthreads();
    sm[t] += a;
    __syncthreads();
  }
  int excl = sm[t] - s;
  if (base + 0 < n) start[base + 0] = excl;
  excl += v0;
  if (base + 1 < n) start[base + 1] = excl;
  excl += v1;
  if (base + 2 < n) start[base + 2] = excl;
  excl += v2;
  if (base + 3 < n) start[base + 3] = excl;
  if (t == 255) bsum[blockIdx.x] = sm[255];
}

// single-block exclusive scan over up to 1024 block sums (in place)
__global__ void __launch_bounds__(256) k_scan2(int* bsum, int nb) {
  __shared__ int sm[256];
  int t = threadIdx.x;
  int base = t * 4;
  int v0 = (base + 0 < nb) ? bsum[base + 0] : 0;
  int v1 = (base + 1 < nb) ? bsum[base + 1] : 0;
  int v2 = (base + 2 < nb) ? bsum[base + 2] : 0;
  int v3 = (base + 3 < nb) ? bsum[base + 3] : 0;
  int s = v0 + v1 + v2 + v3;
  sm[t] = s;
  __syncthreads();
  for (int off = 1; off < 256; off <<= 1) {
    int a = (t >= off) ? sm[t - off] : 0;
    __syncthreads();
    sm[t] += a;
    __syncthreads();
  }
  int excl = sm[t] - s;
  if (base + 0 < nb) bsum[base + 0] = excl;
  excl += v0;
  if (base + 1 < nb) bsum[base + 1] = excl;
  excl += v1;
  if (base + 2 < nb) bsum[base + 2] = excl;
  excl += v2;
  if (base + 3 < nb) bsum[base + 3] = excl;
}

__global__ void __launch_bounds__(256) k_scan3(int* __restrict__ start,
                                               int* __restrict__ cursor,
                                               const int* __restrict__ bsum,
                                               int n, int E) {
  int i = blockIdx.x * 256 + threadIdx.x;
  if (i < n) {
    int v = start[i] + bsum[i >> 10];
    start[i] = v;
    cursor[i] = v;
  } else if (i == n) {
    start[n] = E;
  }
}

// esrc word: src | rel<<17   (src < 2^17, rel < 7; rel==7 reserved as sentinel)
__global__ void __launch_bounds__(256) k_bucket(const int* __restrict__ ei,
                                                const int* __restrict__ et,
                                                int* __restrict__ cursor,
                                                int* __restrict__ esrc, int E) {
  int e = blockIdx.x * 256 + threadIdx.x;
  if (e >= E) return;
  int s = ei[e], d = ei[E + e], r = et[e];
  int pos = atomicAdd(&cursor[(d << 3) + r], 1);
  esrc[pos] = s | (r << 17);
}

// one wave per dst node; node's edges contiguous & rel-sorted.
// 16 lanes per edge (uint2 = 4 ch), 4 edges per VMEM instruction, 4 groups
// unrolled per chunk (16 edges in flight), mask-fmac routing into 7 floatx4.
#define ROUTE(W, F0, F1, F2, F3) do {                                     \
    int _rel = ((W) >> 17) & 7;                                           \
    float _k;                                                             \
    _k = (_rel == 0) ? 1.0f : 0.0f; r0.x += _k*(F0); r0.y += _k*(F1); r0.z += _k*(F2); r0.w += _k*(F3); \
    _k = (_rel == 1) ? 1.0f : 0.0f; r1.x += _k*(F0); r1.y += _k*(F1); r1.z += _k*(F2); r1.w += _k*(F3); \
    _k = (_rel == 2) ? 1.0f : 0.0f; r2.x += _k*(F0); r2.y += _k*(F1); r2.z += _k*(F2); r2.w += _k*(F3); \
    _k = (_rel == 3) ? 1.0f : 0.0f; r3.x += _k*(F0); r3.y += _k*(F1); r3.z += _k*(F2); r3.w += _k*(F3); \
    _k = (_rel == 4) ? 1.0f : 0.0f; r4.x += _k*(F0); r4.y += _k*(F1); r4.z += _k*(F2); r4.w += _k*(F3); \
    _k = (_rel == 5) ? 1.0f : 0.0f; r5.x += _k*(F0); r5.y += _k*(F1); r5.z += _k*(F2); r5.w += _k*(F3); \
    _k = (_rel == 6) ? 1.0f : 0.0f; r6.x += _k*(F0); r6.y += _k*(F1); r6.z += _k*(F2); r6.w += _k*(F3); \
  } while (0)

#define REDUCE4(v) do {                                                   \
    v.x += __shfl_xor(v.x, 16, 64); v.y += __shfl_xor(v.y, 16, 64);       \
    v.z += __shfl_xor(v.z, 16, 64); v.w += __shfl_xor(v.w, 16, 64);       \
    v.x += __shfl_xor(v.x, 32, 64); v.y += __shfl_xor(v.y, 32, 64);       \
    v.z += __shfl_xor(v.z, 32, 64); v.w += __shfl_xor(v.w, 32, 64);       \
  } while (0)

#define EMIT(v, inv, r) do {                                              \
    uint2 t;                                                              \
    t.x = ((unsigned)f2b(v.y * (inv)) << 16) | f2b(v.x * (inv));          \
    t.y = ((unsigned)f2b(v.w * (inv)) << 16) | f2b(v.z * (inv));          \
    *reinterpret_cast<uint2*>(mn + (long)node * (RELS * DIM) + (r) * DIM + (cg << 2)) = t; \
  } while (0)

__global__ void __launch_bounds__(256) k_seg(const int* __restrict__ start,
                                             const int* __restrict__ esrc,
                                             const unsigned short* __restrict__ xb,
                                             unsigned short* __restrict__ mn, int N) {
  int node = (int)(((long)blockIdx.x * 256 + threadIdx.x) >> 6);
  int lane = threadIdx.x & 63;
  if (node >= N) return;
  int sv = 0;
  if (lane < 8) sv = start[(node << 3) + lane];  // boundaries r=0..7
  const int a0 = __shfl(sv, 0, 64);
  const int aE = __shfl(sv, 7, 64);
  const int cg = lane & 15;   // channel group: 4 channels cg*4..+3
  const int eg = lane >> 4;   // edge slot within a 4-edge group

  floatx4 r0 = {0,0,0,0}, r1 = {0,0,0,0}, r2 = {0,0,0,0}, r3 = {0,0,0,0},
          r4 = {0,0,0,0}, r5 = {0,0,0,0}, r6 = {0,0,0,0};

  for (int base = a0; base < aE; base += 64) {
    int idx = base + lane;
    int ew = (idx < aE) ? esrc[idx] : 0x000E0000;  // sentinel: rel=7, src=0
    int m = aE - base; if (m > 64) m = 64;
    for (int c0 = 0; c0 < m; c0 += 16) {
      // 4 group-gathers issued back-to-back (16 edges in flight)
      int w0 = __shfl(ew, c0 + 0 + eg, 64);
      int w1 = __shfl(ew, c0 + 4 + eg, 64);
      int w2 = __shfl(ew, c0 + 8 + eg, 64);
      int w3 = __shfl(ew, c0 + 12 + eg, 64);
      uint2 d0 = *reinterpret_cast<const uint2*>(xb + (((long)(w0 & 0x1FFFF)) << 6) + (cg << 2));
      uint2 d1 = *reinterpret_cast<const uint2*>(xb + (((long)(w1 & 0x1FFFF)) << 6) + (cg << 2));
      uint2 d2 = *reinterpret_cast<const uint2*>(xb + (((long)(w2 & 0x1FFFF)) << 6) + (cg << 2));
      uint2 d3 = *reinterpret_cast<const uint2*>(xb + (((long)(w3 & 0x1FFFF)) << 6) + (cg << 2));
      ROUTE(w0, u2f(d0.x << 16), u2f(d0.x & 0xffff0000u), u2f(d0.y << 16), u2f(d0.y & 0xffff0000u));
      ROUTE(w1, u2f(d1.x << 16), u2f(d1.x & 0xffff0000u), u2f(d1.y << 16), u2f(d1.y & 0xffff0000u));
      ROUTE(w2, u2f(d2.x << 16), u2f(d2.x & 0xffff0000u), u2f(d2.y << 16), u2f(d2.y & 0xffff0000u));
      ROUTE(w3, u2f(d3.x << 16), u2f(d3.x & 0xffff0000u), u2f(d3.y << 16), u2f(d3.y & 0xffff0000u));
    }
  }

  // reduce the 4 edge-slot partials (lanes eg=0..3) down to lanes 0-15
  REDUCE4(r0); REDUCE4(r1); REDUCE4(r2); REDUCE4(r3);
  REDUCE4(r4); REDUCE4(r5); REDUCE4(r6);

  // counts from boundaries (computed while all lanes active)
  int s0 = __shfl(sv, 0, 64), s1 = __shfl(sv, 1, 64), s2 = __shfl(sv, 2, 64),
      s3 = __shfl(sv, 3, 64), s4 = __shfl(sv, 4, 64), s5 = __shfl(sv, 5, 64),
      s6 = __shfl(sv, 6, 64), s7 = __shfl(sv, 7, 64);
  float i0 = __builtin_amdgcn_rcpf(fmaxf((float)(s1 - s0), 1.0f));
  float i1 = __builtin_amdgcn_rcpf(fmaxf((float)(s2 - s1), 1.0f));
  float i2 = __builtin_amdgcn_rcpf(fmaxf((float)(s3 - s2), 1.0f));
  float i3 = __builtin_amdgcn_rcpf(fmaxf((float)(s4 - s3), 1.0f));
  float i4 = __builtin_amdgcn_rcpf(fmaxf((float)(s5 - s4), 1.0f));
  float i5 = __builtin_amdgcn_rcpf(fmaxf((float)(s6 - s5), 1.0f));
  float i6 = __builtin_amdgcn_rcpf(fmaxf((float)(s7 - s6), 1.0f));

  if (lane < 16) {
    EMIT(r0, i0, 0); EMIT(r1, i1, 1); EMIT(r2, i2, 2); EMIT(r3, i3, 3);
    EMIT(r4, i4, 4); EMIT(r5, i5, 5); EMIT(r6, i6, 6);
  }
}

// out[i][:] = [mn[i] | xb[i]] (K=512, bf16) @ Blg + bias
__global__ void __launch_bounds__(256) k_gemm(const unsigned short* __restrict__ mn,
                                              const unsigned short* __restrict__ xb,
                                              const unsigned short* __restrict__ Blg,
                                              const float* __restrict__ bias,
                                              float* __restrict__ out, int N)
{
  __shared__ short Bl[KTOT * DIM];  // 64 KiB, MFMA-fragment order
  const int tid = threadIdx.x;

  {
    const short8* src = reinterpret_cast<const short8*>(Blg);
    short8* dst = reinterpret_cast<short8*>(Bl);
#pragma unroll
    for (int i = 0; i < 16; ++i) dst[tid + i * 256] = src[tid + i * 256];
  }
  __syncthreads();

  const int lane = tid & 63;
  const int wv = tid >> 6;
  const int rowbase = blockIdx.x * 64 + wv * 16;
  const int row16 = lane & 15;
  const int kg = lane >> 4;
  int i = rowbase + row16;
  if (i > N - 1) i = N - 1;

  floatx4 c0 = {0,0,0,0}, c1 = {0,0,0,0}, c2 = {0,0,0,0}, c3 = {0,0,0,0};
  const short8* Bv = reinterpret_cast<const short8*>(Bl);

#pragma unroll
  for (int kk = 0; kk < 16; ++kk) {
    const int r = kk >> 1;
    const int d0 = (kk * 32 + kg * 8) & 63;
    const unsigned short* ap = (r < RELS)
        ? (mn + (long)i * (RELS * DIM) + r * DIM + d0)
        : (xb + (long)i * DIM + d0);
    short8 aa = *reinterpret_cast<const short8*>(ap);
    const int bb = (kk * 4 + kg) * 64 + row16;
    c0 = __builtin_amdgcn_mfma_f32_16x16x32_bf16(aa, Bv[bb],      c0, 0, 0, 0);
    c1 = __builtin_amdgcn_mfma_f32_16x16x32_bf16(aa, Bv[bb + 16], c1, 0, 0, 0);
    c2 = __builtin_amdgcn_mfma_f32_16x16x32_bf16(aa, Bv[bb + 32], c2, 0, 0, 0);
    c3 = __builtin_amdgcn_mfma_f32_16x16x32_bf16(aa, Bv[bb + 48], c3, 0, 0, 0);
  }

  const int rowoff = kg * 4;
#pragma unroll
  for (int t = 0; t < 4; ++t) {
    floatx4 c = (t == 0) ? c0 : (t == 1) ? c1 : (t == 2) ? c2 : c3;
    const int col = t * 16 + row16;
    const float b = bias[col];
#pragma unroll
    for (int q = 0; q < 4; ++q) {
      int row = rowbase + rowoff + q;
      if (row < N) out[(long)row * DIM + col] = c[q] + b;
    }
  }
}

extern "C" void kernel_launch(void* const* d_in, const int* in_sizes, int n_in,
                              void* d_out, int out_size, void* d_ws, size_t ws_size,
                              hipStream_t stream)
{
  const float* x    = (const float*)d_in[0];
  const float* W    = (const float*)d_in[1];
  const float* root = (const float*)d_in[2];
  const float* bias = (const float*)d_in[3];
  const int*   ei   = (const int*)d_in[4];
  const int*   et   = (const int*)d_in[5];
  float* out = (float*)d_out;

  const int N = in_sizes[0] / DIM;
  const int E = in_sizes[4] / 2;
  const int NS = N * 8;  // segments = dst*8 + rel (r=7 bucket always empty)

  // workspace layout
  unsigned short* mn = (unsigned short*)d_ws;            // [N][7][64] bf16
  unsigned short* xb = mn + (size_t)N * RELS * DIM;      // [N][64] bf16
  unsigned short* Blg = xb + (size_t)N * DIM;            // [4096*8] bf16 (64 KiB)
  int* esrc   = (int*)(Blg + 4096 * 8);                  // [E]
  int* deg    = esrc + E;                                // [NS]
  int* start  = deg + NS;                                // [NS+1]
  int* cursor = start + NS + 1;                          // [NS]
  int* bsum   = cursor + NS;                             // [ceil(NS/1024)]

  hipMemsetAsync(deg, 0, (size_t)NS * sizeof(int), stream);
  k_xb<<<(int)(((long)N * DIM / 8 + 255) / 256), 256, 0, stream>>>(x, xb, (long)N * DIM / 8);
  k_wb<<<16, 256, 0, stream>>>(W, root, Blg);
  k_hist<<<(E + 255) / 256, 256, 0, stream>>>(ei + E, et, deg, E);
  int nb = (NS + 1023) / 1024;
  k_scan1<<<nb, 256, 0, stream>>>(deg, start, bsum, NS);
  k_scan2<<<1, 256, 0, stream>>>(bsum, nb);
  k_scan3<<<(NS + 1 + 255) / 256, 256, 0, stream>>>(start, cursor, bsum, NS, E);
  k_bucket<<<(E + 255) / 256, 256, 0, stream>>>(ei, et, cursor, esrc, E);
  k_seg<<<(N + 3) / 4, 256, 0, stream>>>(start, esrc, xb, mn, N);
  k_gemm<<<(N + 63) / 64, 256, 0, stream>>>(mn, xb, Blg, bias, out, N);
}